// Round 1
// baseline (140.586 us; speedup 1.0000x reference)
//
#include <hip/hip_runtime.h>
#include <hip/hip_bf16.h>
#include <math.h>

// ProxyMLS: score = -0.5*(e2@iv^T - 2*e@(mu*iv)^T + const_j)
// pos_e = -32*(score-0.1) = 16*raw + (16*const_j + 3.2);  neg_e = 6.4 - pos_e
// Online per-column (class) max/sums; exact rescale in reductions.

#define N_EMB 4096
#define C_CLS 8192
#define D_DIM 64
#define K_DIM 128   // concat [e^2 | e] x [iv | -2*mu*iv]

typedef __attribute__((ext_vector_type(8))) __bf16 bf16x8;
typedef __attribute__((ext_vector_type(4))) float f32x4;

__device__ __forceinline__ void async_ld16(void* lds, const void* g) {
  __builtin_amdgcn_global_load_lds(
      (__attribute__((address_space(1))) void*)g,
      (__attribute__((address_space(3))) void*)lds, 16, 0, 0);
}

// One wave per row: build bf16 A=[e^2|e] (N x 128), B=[iv|-2*mu*iv] (C x 128),
// const_j = sum_d(mu^2*iv + logvar).
__global__ void k_prep(const float* __restrict__ emb,
                       const float* __restrict__ mp,
                       const float* __restrict__ lvp,
                       __bf16* __restrict__ wsA,
                       __bf16* __restrict__ wsB,
                       float* __restrict__ constv) {
  int wave = (int)((blockIdx.x * blockDim.x + threadIdx.x) >> 6);
  int lane = threadIdx.x & 63;  // lane == d (D_DIM == 64)
  if (wave < N_EMB) {
    float e = emb[wave * D_DIM + lane];
    wsA[wave * K_DIM + lane]         = (__bf16)(e * e);
    wsA[wave * K_DIM + D_DIM + lane] = (__bf16)e;
  } else {
    int j = wave - N_EMB;
    float mu = mp[j * D_DIM + lane];
    float lv = lvp[j * D_DIM + lane];
    float iv = __expf(-lv);
    wsB[j * K_DIM + lane]         = (__bf16)iv;
    wsB[j * K_DIM + D_DIM + lane] = (__bf16)(-2.0f * mu * iv);
    float t = fmaf(mu * mu, iv, lv);
    #pragma unroll
    for (int s = 32; s >= 1; s >>= 1) t += __shfl_xor(t, s);
    if (lane == 0) constv[j] = t;
  }
}

// 128x128 tile per block: bf16 MFMA GEMM (K=128) + fused per-column
// online max / masked exp-sums. Partials -> ws[rb][gcol].
__global__ __launch_bounds__(256, 2) void k_main(
    const __bf16* __restrict__ wsA, const __bf16* __restrict__ wsB,
    const float* __restrict__ constv, const int* __restrict__ labels,
    float* __restrict__ wsM, float* __restrict__ wsP, float* __restrict__ wsN) {
  __shared__ __align__(16) __bf16 As[128][K_DIM];  // 32 KB
  __shared__ __align__(16) __bf16 Bs[128][K_DIM];  // 32 KB  (total 64 KB -> 2 blocks/CU)

  const int tid = threadIdx.x;
  const int rb = blockIdx.x & 31;   // row block (N/128 = 32)
  const int cb = blockIdx.x >> 5;   // col block (C/128 = 64)

  // Stage A,B tiles: contiguous 32 KB each, direct global->LDS DMA, 16B/lane.
  const char* Ag = (const char*)(wsA + (size_t)rb * 128 * K_DIM);
  const char* Bg = (const char*)(wsB + (size_t)cb * 128 * K_DIM);
  char* Al = (char*)&As[0][0];
  char* Bl = (char*)&Bs[0][0];
  #pragma unroll
  for (int it = 0; it < 8; ++it) {
    int off = (it * 256 + tid) * 16;
    async_ld16(Al + off, Ag + off);
  }
  #pragma unroll
  for (int it = 0; it < 8; ++it) {
    int off = (it * 256 + tid) * 16;
    async_ld16(Bl + off, Bg + off);
  }
  __syncthreads();  // drains vmcnt before barrier

  const int wv = tid >> 6, lane = tid & 63;
  const int wr = wv >> 1, wc = wv & 1;     // 2x2 wave grid, 64x64 per wave
  const int quad = lane >> 4, lc = lane & 15;

  f32x4 acc[4][4];
  #pragma unroll
  for (int i = 0; i < 4; ++i)
    #pragma unroll
    for (int j = 0; j < 4; ++j) acc[i][j] = (f32x4){0.f, 0.f, 0.f, 0.f};

  #pragma unroll
  for (int kk = 0; kk < 4; ++kk) {
    const int kof = kk * 32 + quad * 8;  // A[m=lc][k=quad*8+j], B same (B^T form)
    bf16x8 af[4], bfr[4];
    #pragma unroll
    for (int mi = 0; mi < 4; ++mi)
      af[mi] = *(const bf16x8*)&As[wr * 64 + mi * 16 + lc][kof];
    #pragma unroll
    for (int ni = 0; ni < 4; ++ni)
      bfr[ni] = *(const bf16x8*)&Bs[wc * 64 + ni * 16 + lc][kof];
    #pragma unroll
    for (int mi = 0; mi < 4; ++mi)
      #pragma unroll
      for (int ni = 0; ni < 4; ++ni)
        acc[mi][ni] = __builtin_amdgcn_mfma_f32_16x16x32_bf16(
            af[mi], bfr[ni], acc[mi][ni], 0, 0, 0);
  }

  __syncthreads();  // As/Bs dead; alias epilogue scratch onto As
  float* colred = (float*)Al;         // [2][128][3] floats = 3072 B
  int* labels_s = (int*)(Al + 3072);  // 512 B
  float* pc_s   = (float*)(Al + 3584);// 512 B
  if (tid < 128) {
    labels_s[tid] = labels[rb * 128 + tid];
    pc_s[tid] = fmaf(16.0f, constv[cb * 128 + tid], 3.2f);  // 16*const + alpha*margin
  }
  __syncthreads();

  // C/D layout: col = lane&15, row = quad*4 + reg (m89-verified).
  int labv[4][4];
  #pragma unroll
  for (int mi = 0; mi < 4; ++mi)
    #pragma unroll
    for (int r = 0; r < 4; ++r)
      labv[mi][r] = labels_s[wr * 64 + mi * 16 + quad * 4 + r];

  #pragma unroll
  for (int ni = 0; ni < 4; ++ni) {
    const int col_local = wc * 64 + ni * 16 + lc;
    const int gcol = cb * 128 + col_local;
    const float pcv = pc_s[col_local];
    float lmax = -1e30f;
    #pragma unroll
    for (int mi = 0; mi < 4; ++mi)
      #pragma unroll
      for (int r = 0; r < 4; ++r)
        lmax = fmaxf(lmax, fmaf(16.0f, acc[mi][ni][r], pcv));
    lmax = fmaxf(lmax, __shfl_xor(lmax, 16));
    lmax = fmaxf(lmax, __shfl_xor(lmax, 32));  // col max over wave's 64 rows
    float ps = 0.f, ns = 0.f;
    #pragma unroll
    for (int mi = 0; mi < 4; ++mi)
      #pragma unroll
      for (int r = 0; r < 4; ++r) {
        float pe = fmaf(16.0f, acc[mi][ni][r], pcv);
        bool match = (labv[mi][r] == gcol);
        float v = match ? pe : (6.4f - pe);   // neg_e = 2*alpha*margin - pos_e
        float ex = __expf(v - lmax);
        ps += match ? ex : 0.f;
        ns += match ? 0.f : ex;
      }
    ps += __shfl_xor(ps, 16); ps += __shfl_xor(ps, 32);
    ns += __shfl_xor(ns, 16); ns += __shfl_xor(ns, 32);
    if (quad == 0) {
      float* c = &colred[(wr * 128 + col_local) * 3];
      c[0] = lmax; c[1] = ps; c[2] = ns;
    }
  }
  __syncthreads();
  if (tid < 128) {  // merge the two row-halves, write block partials
    const float* c0 = &colred[(0 * 128 + tid) * 3];
    const float* c1 = &colred[(1 * 128 + tid) * 3];
    float M = fmaxf(c0[0], c1[0]);
    float s0 = __expf(c0[0] - M), s1 = __expf(c1[0] - M);
    int gcol = cb * 128 + tid;
    wsM[rb * C_CLS + gcol] = M;
    wsP[rb * C_CLS + gcol] = fmaf(c0[1], s0, c1[1] * s1);
    wsN[rb * C_CLS + gcol] = fmaf(c0[2], s0, c1[2] * s1);
  }
}

// Reduce 32 row-block partials per column (exact rescale to column max).
__global__ void k_red1(const float* __restrict__ wsM, const float* __restrict__ wsP,
                       const float* __restrict__ wsN, float* __restrict__ Mcol,
                       float* __restrict__ Pcol, float* __restrict__ Ncol) {
  int j = blockIdx.x * 256 + threadIdx.x;  // 8192 threads, one per class
  float M = -1e30f;
  #pragma unroll 8
  for (int rb = 0; rb < 32; ++rb) M = fmaxf(M, wsM[rb * C_CLS + j]);
  float ps = 0.f, ns = 0.f;
  #pragma unroll 8
  for (int rb = 0; rb < 32; ++rb) {
    float s = __expf(wsM[rb * C_CLS + j] - M);
    ps = fmaf(wsP[rb * C_CLS + j], s, ps);
    ns = fmaf(wsN[rb * C_CLS + j], s, ns);
  }
  Mcol[j] = M; Pcol[j] = ps; Ncol[j] = ns;
}

// Single block: global m, num_valid (via LDS class-flag), final scalar.
__global__ void k_fin(const float* __restrict__ Mcol, const float* __restrict__ Pcol,
                      const float* __restrict__ Ncol, const int* __restrict__ labels,
                      float* __restrict__ out) {
  __shared__ unsigned char flag[C_CLS];
  __shared__ float redf[256];
  __shared__ float redn[256];
  __shared__ int redi[256];
  const int tid = threadIdx.x;
  for (int i = tid; i < C_CLS; i += 256) flag[i] = 0;
  __syncthreads();
  for (int i = tid; i < N_EMB; i += 256) flag[labels[i]] = 1;
  __syncthreads();
  int nv = 0;
  float M = -1e30f;
  for (int i = tid; i < C_CLS; i += 256) {
    nv += flag[i];
    M = fmaxf(M, Mcol[i]);
  }
  redf[tid] = M; redi[tid] = nv;
  __syncthreads();
  if (tid == 0) {
    float mm = -1e30f; int n = 0;
    for (int i = 0; i < 256; ++i) { mm = fmaxf(mm, redf[i]); n += redi[i]; }
    redf[0] = mm; redi[0] = n;
  }
  __syncthreads();
  const float m = redf[0];
  const int num_valid = redi[0];
  __syncthreads();  // all reads of redf[0]/redi[0] done before reuse
  float pt = 0.f, nt = 0.f;
  for (int i = tid; i < C_CLS; i += 256) {
    float s = __expf(Mcol[i] - m);
    pt += log1pf(Pcol[i] * s);
    nt += log1pf(Ncol[i] * s);
  }
  redf[tid] = pt; redn[tid] = nt;
  __syncthreads();
  if (tid == 0) {
    float sp = 0.f, sn = 0.f;
    for (int i = 0; i < 256; ++i) { sp += redf[i]; sn += redn[i]; }
    out[0] = (sp + (float)C_CLS * m) / (float)num_valid
           + (sn + (float)C_CLS * m) / (float)C_CLS;
  }
}

extern "C" void kernel_launch(void* const* d_in, const int* in_sizes, int n_in,
                              void* d_out, int out_size, void* d_ws, size_t ws_size,
                              hipStream_t stream) {
  const float* emb    = (const float*)d_in[0];
  const int*   labels = (const int*)d_in[1];
  const float* mp     = (const float*)d_in[2];
  const float* lvp    = (const float*)d_in[3];
  float* out = (float*)d_out;

  char* ws = (char*)d_ws;
  __bf16* wsA   = (__bf16*)ws;                            // 4096*128*2 = 1 MB
  __bf16* wsB   = (__bf16*)(ws + (1u << 20));             // 8192*128*2 = 2 MB
  float* constv = (float*)(ws + 3u * (1u << 20));         // 32 KB
  float* wsM    = (float*)(ws + 3u * (1u << 20) + (1u << 15));  // 32*8192*4 = 1 MB
  float* wsP    = wsM + 32 * C_CLS;                       // 1 MB
  float* wsN    = wsP + 32 * C_CLS;                       // 1 MB
  float* Mcol   = wsN + 32 * C_CLS;                       // 32 KB
  float* Pcol   = Mcol + C_CLS;                           // 32 KB
  float* Ncol   = Pcol + C_CLS;                           // 32 KB

  hipLaunchKernelGGL(k_prep, dim3((N_EMB + C_CLS) / 4), dim3(256), 0, stream,
                     emb, mp, lvp, wsA, wsB, constv);
  hipLaunchKernelGGL(k_main, dim3((N_EMB / 128) * (C_CLS / 128)), dim3(256), 0, stream,
                     wsA, wsB, constv, labels, wsM, wsP, wsN);
  hipLaunchKernelGGL(k_red1, dim3(C_CLS / 256), dim3(256), 0, stream,
                     wsM, wsP, wsN, Mcol, Pcol, Ncol);
  hipLaunchKernelGGL(k_fin, dim3(1), dim3(256), 0, stream,
                     Mcol, Pcol, Ncol, labels, out);
}

// Round 2
// 129.853 us; speedup vs baseline: 1.0826x; 1.0826x over previous
//
#include <hip/hip_runtime.h>
#include <hip/hip_bf16.h>
#include <math.h>

// ProxyMLS: score = -0.5*(e2@iv^T - 2*e@(mu*iv)^T + const_j)
// pos_e = -32*(score-0.1) = 16*raw + (16*const_j + 3.2);  neg_e = 6.4 - pos_e
// Online per-column (class) max/sums; exact rescale in reductions.
// R2: XOR-swizzled LDS tiles (kills the 16-way bank conflict on the
// ds_read_b128 fragment loads while keeping global_load_lds DMA), and
// shuffle-parallel k_fin reductions.

#define N_EMB 4096
#define C_CLS 8192
#define D_DIM 64
#define K_DIM 128   // concat [e^2 | e] x [iv | -2*mu*iv]

typedef __attribute__((ext_vector_type(8))) __bf16 bf16x8;
typedef __attribute__((ext_vector_type(4))) float f32x4;

__device__ __forceinline__ void async_ld16(void* lds, const void* g) {
  __builtin_amdgcn_global_load_lds(
      (__attribute__((address_space(1))) void*)g,
      (__attribute__((address_space(3))) void*)lds, 16, 0, 0);
}

// One wave per row: build bf16 A=[e^2|e] (N x 128), B=[iv|-2*mu*iv] (C x 128),
// const_j = sum_d(mu^2*iv + logvar).
__global__ void k_prep(const float* __restrict__ emb,
                       const float* __restrict__ mp,
                       const float* __restrict__ lvp,
                       __bf16* __restrict__ wsA,
                       __bf16* __restrict__ wsB,
                       float* __restrict__ constv) {
  int wave = (int)((blockIdx.x * blockDim.x + threadIdx.x) >> 6);
  int lane = threadIdx.x & 63;  // lane == d (D_DIM == 64)
  if (wave < N_EMB) {
    float e = emb[wave * D_DIM + lane];
    wsA[wave * K_DIM + lane]         = (__bf16)(e * e);
    wsA[wave * K_DIM + D_DIM + lane] = (__bf16)e;
  } else {
    int j = wave - N_EMB;
    float mu = mp[j * D_DIM + lane];
    float lv = lvp[j * D_DIM + lane];
    float iv = __expf(-lv);
    wsB[j * K_DIM + lane]         = (__bf16)iv;
    wsB[j * K_DIM + D_DIM + lane] = (__bf16)(-2.0f * mu * iv);
    float t = fmaf(mu * mu, iv, lv);
    #pragma unroll
    for (int s = 32; s >= 1; s >>= 1) t += __shfl_xor(t, s);
    if (lane == 0) constv[j] = t;
  }
}

// 128x128 tile per block: bf16 MFMA GEMM (K=128) + fused per-column
// online max / masked exp-sums. Partials -> ws[rb][gcol].
//
// LDS layout: tile = 128 rows x 16 chunks (16 B each), row stride 256 B.
// Slot (r, cs) holds GLOBAL chunk (r, cs ^ (r & 15)).  Reader of chunk c
// of row r loads slot c ^ (r & 15); within a quad row&15 == lc, so banks
// are ((c^lc)&7)*4 -> 2 lanes per 4-bank group -> conflict-free (m136).
__global__ __launch_bounds__(256, 2) void k_main(
    const __bf16* __restrict__ wsA, const __bf16* __restrict__ wsB,
    const float* __restrict__ constv, const int* __restrict__ labels,
    float* __restrict__ wsM, float* __restrict__ wsP, float* __restrict__ wsN) {
  __shared__ __align__(16) char As[32768];  // 32 KB
  __shared__ __align__(16) char Bs[32768];  // 32 KB  (64 KB -> 2 blocks/CU)

  const int tid = threadIdx.x;
  const int rb = blockIdx.x & 31;   // row block (N/128 = 32)
  const int cb = blockIdx.x >> 5;   // col block (C/128 = 64)

  const char* Ag = (const char*)(wsA + (size_t)rb * 128 * K_DIM);
  const char* Bg = (const char*)(wsB + (size_t)cb * 128 * K_DIM);
  // Swizzled stage: LDS chunk L=(it*256+tid) is slot (r=L>>4, cs=L&15);
  // source global chunk is (r, cs ^ (r&15)). Same 256 B row-group per
  // 16 lanes -> still fully coalesced at 256 B granularity.
  #pragma unroll
  for (int it = 0; it < 8; ++it) {
    int L = it * 256 + tid;
    int r = L >> 4, cs = L & 15;
    int goff = r * 256 + ((cs ^ (r & 15)) << 4);
    async_ld16(As + L * 16, Ag + goff);
  }
  #pragma unroll
  for (int it = 0; it < 8; ++it) {
    int L = it * 256 + tid;
    int r = L >> 4, cs = L & 15;
    int goff = r * 256 + ((cs ^ (r & 15)) << 4);
    async_ld16(Bs + L * 16, Bg + goff);
  }
  __syncthreads();  // drains vmcnt before barrier

  const int wv = tid >> 6, lane = tid & 63;
  const int wr = wv >> 1, wc = wv & 1;     // 2x2 wave grid, 64x64 per wave
  const int quad = lane >> 4, lc = lane & 15;

  f32x4 acc[4][4];
  #pragma unroll
  for (int i = 0; i < 4; ++i)
    #pragma unroll
    for (int j = 0; j < 4; ++j) acc[i][j] = (f32x4){0.f, 0.f, 0.f, 0.f};

  #pragma unroll
  for (int kk = 0; kk < 4; ++kk) {
    const int c = kk * 4 + quad;          // wanted K-chunk (16 B units)
    const int cofs = (c ^ lc) << 4;       // swizzled byte offset (row&15==lc)
    bf16x8 af[4], bfr[4];
    #pragma unroll
    for (int mi = 0; mi < 4; ++mi)
      af[mi] = *(const bf16x8*)(As + (wr * 64 + mi * 16 + lc) * 256 + cofs);
    #pragma unroll
    for (int ni = 0; ni < 4; ++ni)
      bfr[ni] = *(const bf16x8*)(Bs + (wc * 64 + ni * 16 + lc) * 256 + cofs);
    #pragma unroll
    for (int mi = 0; mi < 4; ++mi)
      #pragma unroll
      for (int ni = 0; ni < 4; ++ni)
        acc[mi][ni] = __builtin_amdgcn_mfma_f32_16x16x32_bf16(
            af[mi], bfr[ni], acc[mi][ni], 0, 0, 0);
  }

  __syncthreads();  // As/Bs dead; alias epilogue scratch onto As
  float* colred = (float*)As;         // [2][128][3] floats = 3072 B
  int* labels_s = (int*)(As + 3072);  // 512 B
  float* pc_s   = (float*)(As + 3584);// 512 B
  if (tid < 128) {
    labels_s[tid] = labels[rb * 128 + tid];
    pc_s[tid] = fmaf(16.0f, constv[cb * 128 + tid], 3.2f);  // 16*const + alpha*margin
  }
  __syncthreads();

  // C/D layout: col = lane&15, row = quad*4 + reg (m89-verified).
  int labv[4][4];
  #pragma unroll
  for (int mi = 0; mi < 4; ++mi)
    #pragma unroll
    for (int r = 0; r < 4; ++r)
      labv[mi][r] = labels_s[wr * 64 + mi * 16 + quad * 4 + r];

  #pragma unroll
  for (int ni = 0; ni < 4; ++ni) {
    const int col_local = wc * 64 + ni * 16 + lc;
    const int gcol = cb * 128 + col_local;
    const float pcv = pc_s[col_local];
    float lmax = -1e30f;
    #pragma unroll
    for (int mi = 0; mi < 4; ++mi)
      #pragma unroll
      for (int r = 0; r < 4; ++r)
        lmax = fmaxf(lmax, fmaf(16.0f, acc[mi][ni][r], pcv));
    lmax = fmaxf(lmax, __shfl_xor(lmax, 16));
    lmax = fmaxf(lmax, __shfl_xor(lmax, 32));  // col max over wave's 64 rows
    float ps = 0.f, ns = 0.f;
    #pragma unroll
    for (int mi = 0; mi < 4; ++mi)
      #pragma unroll
      for (int r = 0; r < 4; ++r) {
        float pe = fmaf(16.0f, acc[mi][ni][r], pcv);
        bool match = (labv[mi][r] == gcol);
        float v = match ? pe : (6.4f - pe);   // neg_e = 2*alpha*margin - pos_e
        float ex = __expf(v - lmax);
        ps += match ? ex : 0.f;
        ns += match ? 0.f : ex;
      }
    ps += __shfl_xor(ps, 16); ps += __shfl_xor(ps, 32);
    ns += __shfl_xor(ns, 16); ns += __shfl_xor(ns, 32);
    if (quad == 0) {
      float* c = &colred[(wr * 128 + col_local) * 3];
      c[0] = lmax; c[1] = ps; c[2] = ns;
    }
  }
  __syncthreads();
  if (tid < 128) {  // merge the two row-halves, write block partials
    const float* c0 = &colred[(0 * 128 + tid) * 3];
    const float* c1 = &colred[(1 * 128 + tid) * 3];
    float M = fmaxf(c0[0], c1[0]);
    float s0 = __expf(c0[0] - M), s1 = __expf(c1[0] - M);
    int gcol = cb * 128 + tid;
    wsM[rb * C_CLS + gcol] = M;
    wsP[rb * C_CLS + gcol] = fmaf(c0[1], s0, c1[1] * s1);
    wsN[rb * C_CLS + gcol] = fmaf(c0[2], s0, c1[2] * s1);
  }
}

// Reduce 32 row-block partials per column (exact rescale to column max).
__global__ void k_red1(const float* __restrict__ wsM, const float* __restrict__ wsP,
                       const float* __restrict__ wsN, float* __restrict__ Mcol,
                       float* __restrict__ Pcol, float* __restrict__ Ncol) {
  int j = blockIdx.x * 256 + threadIdx.x;  // 8192 threads, one per class
  float M = -1e30f;
  #pragma unroll 8
  for (int rb = 0; rb < 32; ++rb) M = fmaxf(M, wsM[rb * C_CLS + j]);
  float ps = 0.f, ns = 0.f;
  #pragma unroll 8
  for (int rb = 0; rb < 32; ++rb) {
    float s = __expf(wsM[rb * C_CLS + j] - M);
    ps = fmaf(wsP[rb * C_CLS + j], s, ps);
    ns = fmaf(wsN[rb * C_CLS + j], s, ns);
  }
  Mcol[j] = M; Pcol[j] = ps; Ncol[j] = ns;
}

// Single block: global m, num_valid (via LDS class-flag), final scalar.
__global__ void k_fin(const float* __restrict__ Mcol, const float* __restrict__ Pcol,
                      const float* __restrict__ Ncol, const int* __restrict__ labels,
                      float* __restrict__ out) {
  __shared__ unsigned char flag[C_CLS];
  __shared__ float sA[4], sB[4];
  __shared__ int sI[4];
  const int tid = threadIdx.x;
  const int wv = tid >> 6, lane = tid & 63;
  for (int i = tid; i < C_CLS; i += 256) flag[i] = 0;
  __syncthreads();
  for (int i = tid; i < N_EMB; i += 256) flag[labels[i]] = 1;
  __syncthreads();
  int nv = 0;
  float M = -1e30f;
  for (int i = tid; i < C_CLS; i += 256) {
    nv += flag[i];
    M = fmaxf(M, Mcol[i]);
  }
  #pragma unroll
  for (int s = 32; s >= 1; s >>= 1) {
    M = fmaxf(M, __shfl_xor(M, s));
    nv += __shfl_xor(nv, s);
  }
  if (lane == 0) { sA[wv] = M; sI[wv] = nv; }
  __syncthreads();
  const float m = fmaxf(fmaxf(sA[0], sA[1]), fmaxf(sA[2], sA[3]));
  const int num_valid = sI[0] + sI[1] + sI[2] + sI[3];
  __syncthreads();
  float pt = 0.f, nt = 0.f;
  for (int i = tid; i < C_CLS; i += 256) {
    float s = __expf(Mcol[i] - m);
    pt += log1pf(Pcol[i] * s);
    nt += log1pf(Ncol[i] * s);
  }
  #pragma unroll
  for (int s = 32; s >= 1; s >>= 1) {
    pt += __shfl_xor(pt, s);
    nt += __shfl_xor(nt, s);
  }
  if (lane == 0) { sA[wv] = pt; sB[wv] = nt; }
  __syncthreads();
  if (tid == 0) {
    float sp = sA[0] + sA[1] + sA[2] + sA[3];
    float sn = sB[0] + sB[1] + sB[2] + sB[3];
    out[0] = (sp + (float)C_CLS * m) / (float)num_valid
           + (sn + (float)C_CLS * m) / (float)C_CLS;
  }
}

extern "C" void kernel_launch(void* const* d_in, const int* in_sizes, int n_in,
                              void* d_out, int out_size, void* d_ws, size_t ws_size,
                              hipStream_t stream) {
  const float* emb    = (const float*)d_in[0];
  const int*   labels = (const int*)d_in[1];
  const float* mp     = (const float*)d_in[2];
  const float* lvp    = (const float*)d_in[3];
  float* out = (float*)d_out;

  char* ws = (char*)d_ws;
  __bf16* wsA   = (__bf16*)ws;                            // 4096*128*2 = 1 MB
  __bf16* wsB   = (__bf16*)(ws + (1u << 20));             // 8192*128*2 = 2 MB
  float* constv = (float*)(ws + 3u * (1u << 20));         // 32 KB
  float* wsM    = (float*)(ws + 3u * (1u << 20) + (1u << 15));  // 32*8192*4 = 1 MB
  float* wsP    = wsM + 32 * C_CLS;                       // 1 MB
  float* wsN    = wsP + 32 * C_CLS;                       // 1 MB
  float* Mcol   = wsN + 32 * C_CLS;                       // 32 KB
  float* Pcol   = Mcol + C_CLS;                           // 32 KB
  float* Ncol   = Pcol + C_CLS;                           // 32 KB

  hipLaunchKernelGGL(k_prep, dim3((N_EMB + C_CLS) / 4), dim3(256), 0, stream,
                     emb, mp, lvp, wsA, wsB, constv);
  hipLaunchKernelGGL(k_main, dim3((N_EMB / 128) * (C_CLS / 128)), dim3(256), 0, stream,
                     wsA, wsB, constv, labels, wsM, wsP, wsN);
  hipLaunchKernelGGL(k_red1, dim3(C_CLS / 256), dim3(256), 0, stream,
                     wsM, wsP, wsN, Mcol, Pcol, Ncol);
  hipLaunchKernelGGL(k_fin, dim3(1), dim3(256), 0, stream,
                     Mcol, Pcol, Ncol, labels, out);
}

// Round 3
// 125.867 us; speedup vs baseline: 1.1169x; 1.0317x over previous
//
#include <hip/hip_runtime.h>
#include <hip/hip_bf16.h>
#include <math.h>

// ProxyMLS: score = -0.5*(e2@iv^T - 2*e@(mu*iv)^T + const_j)
// pos_e = -32*(score-0.1) = 16*raw + (16*const_j + 3.2);  neg_e = 6.4 - pos_e
// Online per-column (class) max/sums; exact rescale in reductions.
// R3: 32x32x16 MFMA (fewer MFMA issues, 1 shuffle per col-reduce instead
// of 2), fused red1+fin via last-block arrival, int4 label fetches.

#define N_EMB 4096
#define C_CLS 8192
#define D_DIM 64
#define K_DIM 128   // concat [e^2 | e] x [iv | -2*mu*iv]

typedef __attribute__((ext_vector_type(8))) __bf16 bf16x8;
typedef __attribute__((ext_vector_type(16))) float f32x16;
typedef __attribute__((ext_vector_type(4))) int i32x4;

__device__ __forceinline__ void async_ld16(void* lds, const void* g) {
  __builtin_amdgcn_global_load_lds(
      (__attribute__((address_space(1))) void*)g,
      (__attribute__((address_space(3))) void*)lds, 16, 0, 0);
}

// One wave per row: build bf16 A=[e^2|e] (N x 128), B=[iv|-2*mu*iv] (C x 128),
// const_j = sum_d(mu^2*iv + logvar). Also zeroes the arrival counter.
__global__ void k_prep(const float* __restrict__ emb,
                       const float* __restrict__ mp,
                       const float* __restrict__ lvp,
                       __bf16* __restrict__ wsA,
                       __bf16* __restrict__ wsB,
                       float* __restrict__ constv,
                       int* __restrict__ counter) {
  if (blockIdx.x == 0 && threadIdx.x == 0) *counter = 0;  // ws is 0xAA-poisoned
  int wave = (int)((blockIdx.x * blockDim.x + threadIdx.x) >> 6);
  int lane = threadIdx.x & 63;  // lane == d (D_DIM == 64)
  if (wave < N_EMB) {
    float e = emb[wave * D_DIM + lane];
    wsA[wave * K_DIM + lane]         = (__bf16)(e * e);
    wsA[wave * K_DIM + D_DIM + lane] = (__bf16)e;
  } else {
    int j = wave - N_EMB;
    float mu = mp[j * D_DIM + lane];
    float lv = lvp[j * D_DIM + lane];
    float iv = __expf(-lv);
    wsB[j * K_DIM + lane]         = (__bf16)iv;
    wsB[j * K_DIM + D_DIM + lane] = (__bf16)(-2.0f * mu * iv);
    float t = fmaf(mu * mu, iv, lv);
    #pragma unroll
    for (int s = 32; s >= 1; s >>= 1) t += __shfl_xor(t, s);
    if (lane == 0) constv[j] = t;
  }
}

// 128x128 tile per block: bf16 32x32x16 MFMA GEMM (K=128) + fused per-column
// online max / masked exp-sums. Partials -> ws[rb][gcol].
//
// LDS layout: tile = 128 rows x 16 chunks (16 B each), row stride 256 B.
// Slot (r, cs) holds GLOBAL chunk (r, cs ^ (r & 15)). Reader of chunk c of
// row r loads slot c ^ (r & 15); bank group = (c ^ (r&15)) & 7 -> 2 lanes
// per 4-bank group per 16-lane quarter -> conflict-free (m136).
__global__ __launch_bounds__(256, 2) void k_main(
    const __bf16* __restrict__ wsA, const __bf16* __restrict__ wsB,
    const float* __restrict__ constv, const int* __restrict__ labels,
    float* __restrict__ wsM, float* __restrict__ wsP, float* __restrict__ wsN) {
  __shared__ __align__(16) char As[32768];  // 32 KB
  __shared__ __align__(16) char Bs[32768];  // 32 KB  (64 KB -> 2 blocks/CU)

  const int tid = threadIdx.x;
  const int rb = blockIdx.x & 31;   // row block (N/128 = 32)
  const int cb = blockIdx.x >> 5;   // col block (C/128 = 64)

  const char* Ag = (const char*)(wsA + (size_t)rb * 128 * K_DIM);
  const char* Bg = (const char*)(wsB + (size_t)cb * 128 * K_DIM);
  #pragma unroll
  for (int it = 0; it < 8; ++it) {
    int L = it * 256 + tid;
    int r = L >> 4, cs = L & 15;
    int goff = r * 256 + ((cs ^ (r & 15)) << 4);
    async_ld16(As + L * 16, Ag + goff);
  }
  #pragma unroll
  for (int it = 0; it < 8; ++it) {
    int L = it * 256 + tid;
    int r = L >> 4, cs = L & 15;
    int goff = r * 256 + ((cs ^ (r & 15)) << 4);
    async_ld16(Bs + L * 16, Bg + goff);
  }
  __syncthreads();  // drains vmcnt before barrier

  const int wv = tid >> 6, lane = tid & 63;
  const int wr = wv >> 1, wc = wv & 1;   // 2x2 wave grid, 64x64 per wave
  const int l31 = lane & 31, kg = lane >> 5;  // A/B frag: row=l31, k=kg*8+j
  const int l15 = lane & 15;

  f32x16 acc[2][2];
  #pragma unroll
  for (int mi = 0; mi < 2; ++mi)
    #pragma unroll
    for (int ni = 0; ni < 2; ++ni)
      #pragma unroll
      for (int r = 0; r < 16; ++r) acc[mi][ni][r] = 0.f;

  #pragma unroll
  for (int kk = 0; kk < 8; ++kk) {       // K = 8 steps of 16
    const int c = kk * 2 + kg;           // wanted 16B K-chunk
    const int cofs = (c ^ l15) << 4;     // swizzled byte offset (row&15==l15)
    bf16x8 af[2], bfr[2];
    #pragma unroll
    for (int mi = 0; mi < 2; ++mi)
      af[mi] = *(const bf16x8*)(As + (wr * 64 + mi * 32 + l31) * 256 + cofs);
    #pragma unroll
    for (int ni = 0; ni < 2; ++ni)
      bfr[ni] = *(const bf16x8*)(Bs + (wc * 64 + ni * 32 + l31) * 256 + cofs);
    #pragma unroll
    for (int mi = 0; mi < 2; ++mi)
      #pragma unroll
      for (int ni = 0; ni < 2; ++ni)
        acc[mi][ni] = __builtin_amdgcn_mfma_f32_32x32x16_bf16(
            af[mi], bfr[ni], acc[mi][ni], 0, 0, 0);
  }

  __syncthreads();  // As/Bs dead; alias epilogue scratch onto As
  float* colred = (float*)As;         // [2][128][3] floats = 3072 B
  int* labels_s = (int*)(As + 3072);  // 512 B (16B-aligned)
  float* pc_s   = (float*)(As + 3584);// 512 B
  if (tid < 128) {
    labels_s[tid] = labels[rb * 128 + tid];
    pc_s[tid] = fmaf(16.0f, constv[cb * 128 + tid], 3.2f);  // 16*const+alpha*margin
  }
  __syncthreads();

  // C/D layout (32x32, m74/m101): col = lane&31, row = (reg&3)+8*(reg>>2)+4*kg.
  i32x4 labv[2][4];  // labv[mi][g] = labels of rows base+{0..3}, base=mi*32+4*kg+8*g
  #pragma unroll
  for (int mi = 0; mi < 2; ++mi)
    #pragma unroll
    for (int g = 0; g < 4; ++g)
      labv[mi][g] = *(const i32x4*)&labels_s[wr * 64 + mi * 32 + 4 * kg + 8 * g];

  #pragma unroll
  for (int ni = 0; ni < 2; ++ni) {
    const int col_local = wc * 64 + ni * 32 + l31;
    const int gcol = cb * 128 + col_local;
    const float pcv = pc_s[col_local];
    float lmax = -1e30f;
    #pragma unroll
    for (int mi = 0; mi < 2; ++mi)
      #pragma unroll
      for (int r = 0; r < 16; ++r)
        lmax = fmaxf(lmax, fmaf(16.0f, acc[mi][ni][r], pcv));
    lmax = fmaxf(lmax, __shfl_xor(lmax, 32));  // other kg half covers other rows
    float ps = 0.f, ns = 0.f;
    #pragma unroll
    for (int mi = 0; mi < 2; ++mi)
      #pragma unroll
      for (int r = 0; r < 16; ++r) {
        float pe = fmaf(16.0f, acc[mi][ni][r], pcv);
        bool match = (labv[mi][r >> 2][r & 3] == gcol);
        float v = match ? pe : (6.4f - pe);   // neg_e = 2*alpha*margin - pos_e
        float ex = __expf(v - lmax);
        ps += match ? ex : 0.f;
        ns += match ? 0.f : ex;
      }
    ps += __shfl_xor(ps, 32);
    ns += __shfl_xor(ns, 32);
    if (kg == 0) {
      float* cr = &colred[(wr * 128 + col_local) * 3];
      cr[0] = lmax; cr[1] = ps; cr[2] = ns;
    }
  }
  __syncthreads();
  if (tid < 128) {  // merge the two row-halves, write block partials
    const float* c0 = &colred[(0 * 128 + tid) * 3];
    const float* c1 = &colred[(1 * 128 + tid) * 3];
    float M = fmaxf(c0[0], c1[0]);
    float s0 = __expf(c0[0] - M), s1 = __expf(c1[0] - M);
    int gcol = cb * 128 + tid;
    wsM[rb * C_CLS + gcol] = M;
    wsP[rb * C_CLS + gcol] = fmaf(c0[1], s0, c1[1] * s1);
    wsN[rb * C_CLS + gcol] = fmaf(c0[2], s0, c1[2] * s1);
  }
}

// Fused: reduce 32 row-block partials per column, then last-arriving block
// computes the final scalar (global m, num_valid, log1p sums).
__global__ __launch_bounds__(256) void k_red(
    const float* __restrict__ wsM, const float* __restrict__ wsP,
    const float* __restrict__ wsN, const int* __restrict__ labels,
    int* __restrict__ counter, float* __restrict__ Mcol,
    float* __restrict__ Pcol, float* __restrict__ Ncol,
    float* __restrict__ out) {
  __shared__ unsigned char flag[C_CLS];  // used only by the last block
  __shared__ float sA[4], sB[4];
  __shared__ int sI[4];
  __shared__ int s_ticket;
  const int tid = threadIdx.x;
  const int j = blockIdx.x * 256 + tid;  // 32 blocks x 256 = one thread/class

  float mv[32];
  float M = -1e30f;
  #pragma unroll
  for (int rb = 0; rb < 32; ++rb) {
    mv[rb] = wsM[rb * C_CLS + j];
    M = fmaxf(M, mv[rb]);
  }
  float ps = 0.f, ns = 0.f;
  #pragma unroll
  for (int rb = 0; rb < 32; ++rb) {
    float s = __expf(mv[rb] - M);
    ps = fmaf(wsP[rb * C_CLS + j], s, ps);
    ns = fmaf(wsN[rb * C_CLS + j], s, ns);
  }
  Mcol[j] = M; Pcol[j] = ps; Ncol[j] = ns;

  __threadfence();   // make this block's Mcol/Pcol/Ncol device-visible
  __syncthreads();
  if (tid == 0) s_ticket = atomicAdd(counter, 1);
  __syncthreads();
  if (s_ticket != 31) return;  // not the last block
  __threadfence();   // acquire: observe all other blocks' writes

  const int wv = tid >> 6, lane = tid & 63;
  for (int i = tid; i < C_CLS; i += 256) flag[i] = 0;
  __syncthreads();
  for (int i = tid; i < N_EMB; i += 256) flag[labels[i]] = 1;
  __syncthreads();
  int nv = 0;
  float gm = -1e30f;
  for (int i = tid; i < C_CLS; i += 256) {
    nv += flag[i];
    gm = fmaxf(gm, Mcol[i]);
  }
  #pragma unroll
  for (int s = 32; s >= 1; s >>= 1) {
    gm = fmaxf(gm, __shfl_xor(gm, s));
    nv += __shfl_xor(nv, s);
  }
  if (lane == 0) { sA[wv] = gm; sI[wv] = nv; }
  __syncthreads();
  const float m = fmaxf(fmaxf(sA[0], sA[1]), fmaxf(sA[2], sA[3]));
  const int num_valid = sI[0] + sI[1] + sI[2] + sI[3];
  __syncthreads();
  float pt = 0.f, nt = 0.f;
  for (int i = tid; i < C_CLS; i += 256) {
    float s = __expf(Mcol[i] - m);
    pt += log1pf(Pcol[i] * s);
    nt += log1pf(Ncol[i] * s);
  }
  #pragma unroll
  for (int s = 32; s >= 1; s >>= 1) {
    pt += __shfl_xor(pt, s);
    nt += __shfl_xor(nt, s);
  }
  if (lane == 0) { sA[wv] = pt; sB[wv] = nt; }
  __syncthreads();
  if (tid == 0) {
    float sp = sA[0] + sA[1] + sA[2] + sA[3];
    float sn = sB[0] + sB[1] + sB[2] + sB[3];
    out[0] = (sp + (float)C_CLS * m) / (float)num_valid
           + (sn + (float)C_CLS * m) / (float)C_CLS;
  }
}

extern "C" void kernel_launch(void* const* d_in, const int* in_sizes, int n_in,
                              void* d_out, int out_size, void* d_ws, size_t ws_size,
                              hipStream_t stream) {
  const float* emb    = (const float*)d_in[0];
  const int*   labels = (const int*)d_in[1];
  const float* mp     = (const float*)d_in[2];
  const float* lvp    = (const float*)d_in[3];
  float* out = (float*)d_out;

  char* ws = (char*)d_ws;
  __bf16* wsA   = (__bf16*)ws;                            // 4096*128*2 = 1 MB
  __bf16* wsB   = (__bf16*)(ws + (1u << 20));             // 8192*128*2 = 2 MB
  float* constv = (float*)(ws + 3u * (1u << 20));         // 32 KB
  float* wsM    = (float*)(ws + 3u * (1u << 20) + (1u << 15));  // 32*8192*4 = 1 MB
  float* wsP    = wsM + 32 * C_CLS;                       // 1 MB
  float* wsN    = wsP + 32 * C_CLS;                       // 1 MB
  float* Mcol   = wsN + 32 * C_CLS;                       // 32 KB
  float* Pcol   = Mcol + C_CLS;                           // 32 KB
  float* Ncol   = Pcol + C_CLS;                           // 32 KB
  int*   counter = (int*)(Ncol + C_CLS);

  hipLaunchKernelGGL(k_prep, dim3((N_EMB + C_CLS) / 4), dim3(256), 0, stream,
                     emb, mp, lvp, wsA, wsB, constv, counter);
  hipLaunchKernelGGL(k_main, dim3((N_EMB / 128) * (C_CLS / 128)), dim3(256), 0, stream,
                     wsA, wsB, constv, labels, wsM, wsP, wsN);
  hipLaunchKernelGGL(k_red, dim3(C_CLS / 256), dim3(256), 0, stream,
                     wsM, wsP, wsN, labels, counter, Mcol, Pcol, Ncol, out);
}